// Round 16
// baseline (522.569 us; speedup 1.0000x reference)
//
#include <hip/hip_runtime.h>
#include <math.h>

#define N_NODES 50000
#define N_EDGES 800000
#define N_GRAPHS 512
#define M_PAD 50048   // N_NODES rounded up to 128
#define SEG_SZ 6250   // N_NODES / 8 (per-XCD dst segment)
#define EPT 8         // edges per thread per count/fill block
#define SEG_BLOCKS 391            // ceil(N_EDGES / (256*EPT))
#define COUNT_BLOCKS (SEG_BLOCKS * 8)

typedef unsigned char u8;
typedef unsigned short u16;
typedef unsigned int u32;
typedef long i64;
using floatx4 = __attribute__((ext_vector_type(4))) float;
using floatx2 = __attribute__((ext_vector_type(2))) float;

// f32 -> OCP e4m3 (single byte via HW pack)
__device__ __forceinline__ u8 f2fp8(float v) {
    return (u8)(__builtin_amdgcn_cvt_pk_fp8_f32(v, v, 0, false) & 0xFF);
}
__device__ __forceinline__ u32 pack4fp8(float a, float b, float c, float d) {
    u32 p = __builtin_amdgcn_cvt_pk_fp8_f32(a, b, 0, false);
    return __builtin_amdgcn_cvt_pk_fp8_f32(c, d, p, true);
}
// accumulate 16 fp8 (one uint4) into acc[16]
__device__ __forceinline__ void acc16fp8(float* acc, uint4 u) {
    const u32 w[4] = {u.x, u.y, u.z, u.w};
    #pragma unroll
    for (int j = 0; j < 4; ++j) {
        floatx2 lo = __builtin_amdgcn_cvt_pk_f32_fp8((int)w[j], false);
        floatx2 hi = __builtin_amdgcn_cvt_pk_f32_fp8((int)w[j], true);
        acc[j * 4 + 0] += lo[0]; acc[j * 4 + 1] += lo[1];
        acc[j * 4 + 2] += hi[0]; acc[j * 4 + 3] += hi[1];
    }
}

// async global->LDS, 16 B per lane; LDS dest = base + lane*16 (wave-uniform base)
__device__ __forceinline__ void load_lds16(const u8* g, u8* l) {
    __builtin_amdgcn_global_load_lds(
        (const __attribute__((address_space(1))) u32*)g,
        (__attribute__((address_space(3))) u32*)l, 16, 0, 0);
}
template<int N> __device__ __forceinline__ void waitcnt_vm() {
    __builtin_amdgcn_s_waitcnt(0x0F70 | N);
}
__device__ __forceinline__ void raw_barrier() {
    asm volatile("s_barrier" ::: "memory");
}

// ---------------------------------------------------------------------------
// prep kernel: XCD-partitioned degree count (blocks 0..COUNT_BLOCKS) +
// all dtype conversions (remaining blocks) — independent work, one launch.
// ---------------------------------------------------------------------------
__global__ __launch_bounds__(256) void prep_kernel(
    const int* __restrict__ dst, int* __restrict__ degi,
    const float* __restrict__ x,
    const float* __restrict__ Wl1, const float* __restrict__ Wr1,
    const float* __restrict__ Wl2, const float* __restrict__ Wr2,
    const float* __restrict__ Wl3, const float* __restrict__ Wr3,
    const float* __restrict__ Wf1, const float* __restrict__ Wf2,
    u8* __restrict__ abuf1,
    u8* __restrict__ wb1, u8* __restrict__ wb2, u8* __restrict__ wb3,
    float* __restrict__ Wf1T, float* __restrict__ Wf2T)
{
    if (blockIdx.x < COUNT_BLOCKS) {
        const int bx = blockIdx.x;
        const int seg = bx & 7;
        const int lo = seg * SEG_SZ, hi = lo + SEG_SZ;
        int e = (bx >> 3) * (256 * EPT) + threadIdx.x;
        #pragma unroll
        for (int j = 0; j < EPT; ++j, e += 256) {
            if (e < N_EDGES) {
                int d = dst[e];
                if (d >= lo && d < hi) atomicAdd(&degi[d], 1);
            }
        }
        return;
    }
    int i = (blockIdx.x - COUNT_BLOCKS) * 256 + threadIdx.x;
    if (i < N_NODES * 16) {
        int n = i >> 4, c = (i & 15) * 4;
        float v[4];
        #pragma unroll
        for (int j = 0; j < 4; ++j) {
            int cc = c + j;
            v[j] = (cc < 50) ? x[n * 50 + cc] : 0.0f;
        }
        *(u32*)(abuf1 + (size_t)n * 128 + 64 + c) = pack4fp8(v[0], v[1], v[2], v[3]);
        return;
    }
    i -= N_NODES * 16;
    if (i < 128 * 64) {
        int o = i / 64, c = i % 64;
        float vl = (c < 50) ? Wl1[o * 50 + c] : 0.0f;
        float vr = (c < 50) ? Wr1[o * 50 + c] : 0.0f;
        wb1[(size_t)o * 128 + c] = f2fp8(vl);
        wb1[(size_t)o * 128 + 64 + c] = f2fp8(vr);
        return;
    }
    i -= 128 * 64;
    if (i < 256 * 128) {
        int o = i / 128, c = i % 128;
        wb2[(size_t)o * 256 + c] = f2fp8(Wl2[o * 128 + c]);
        wb2[(size_t)o * 256 + 128 + c] = f2fp8(Wr2[o * 128 + c]);
        return;
    }
    i -= 256 * 128;
    if (i < 512 * 256) {
        int o = i / 256, c = i % 256;
        wb3[(size_t)o * 512 + c] = f2fp8(Wl3[o * 256 + c]);
        wb3[(size_t)o * 512 + 256 + c] = f2fp8(Wr3[o * 256 + c]);
        return;
    }
    i -= 512 * 256;
    if (i < 256 * 512) {   // Wf1T[k][o] = Wf1[o][k]
        int o = i >> 9, k = i & 511;
        Wf1T[(size_t)k * 256 + o] = Wf1[(size_t)o * 512 + k];
        return;
    }
    i -= 256 * 512;
    if (i < 128 * 256) {   // Wf2T[k][o] = Wf2[o][k]
        int o = i >> 8, k = i & 255;
        Wf2T[(size_t)k * 128 + o] = Wf2[(size_t)o * 256 + k];
    }
}

// ---------------------------------------------------------------------------
// single-block scan: exclusive prefix of degi -> starts, plus gstart from
// sorted batch, plus cursor zeroing (replaces scan1/scan2/scan3/gstart).
// 1024 threads, 49 elements each.
// ---------------------------------------------------------------------------
__global__ __launch_bounds__(1024) void scan_all_kernel(
    const int* __restrict__ degi, int* __restrict__ starts,
    const int* __restrict__ batch, int* __restrict__ gstart,
    int* __restrict__ cursor)
{
    __shared__ int ps[1024];
    const int t = threadIdx.x;
    const int CH = 49;                       // 1024*49 = 50176 >= N_NODES
    const int lo = t * CH;
    const int hi = (lo + CH < N_NODES) ? lo + CH : N_NODES;
    int s = 0;
    for (int i = lo; i < hi; ++i) s += degi[i];
    ps[t] = s;
    __syncthreads();
    for (int off = 1; off < 1024; off <<= 1) {
        int v = (t >= off) ? ps[t - off] : 0;
        __syncthreads();
        ps[t] += v;
        __syncthreads();
    }
    int run = (t == 0) ? 0 : ps[t - 1];
    for (int i = lo; i < hi; ++i) { starts[i] = run; run += degi[i]; }
    if (t == 1023) starts[N_NODES] = ps[1023];
    // gstart from sorted batch
    for (int i = lo; i < hi; ++i) {
        int b = batch[i];
        int bp = (i == 0) ? -1 : batch[i - 1];
        for (int g = bp + 1; g <= b; ++g) gstart[g] = i;
        if (i == N_NODES - 1)
            for (int g = b + 1; g <= N_GRAPHS; ++g) gstart[g] = N_NODES;
    }
    // zero cursor for fill
    for (int i = t; i < 50176; i += 1024) cursor[i] = 0;
}

// ---------------------------------------------------------------------------
// CSR fill — XCD-partitioned (R9, confirmed win)
// ---------------------------------------------------------------------------
__global__ __launch_bounds__(256) void fill_seg_kernel(const int* __restrict__ src,
                                                       const int* __restrict__ dst,
                                                       const int* __restrict__ starts,
                                                       int* __restrict__ cursor,
                                                       u16* __restrict__ csr) {
    const int seg = blockIdx.x & 7;
    const int lo = seg * SEG_SZ, hi = lo + SEG_SZ;
    int e = (blockIdx.x >> 3) * (256 * EPT) + threadIdx.x;
    #pragma unroll
    for (int j = 0; j < EPT; ++j, e += 256) {
        if (e < N_EDGES) {
            int d = dst[e];
            if (d >= lo && d < hi) {
                int p = atomicAdd(&cursor[d], 1);
                csr[starts[d] + p] = (u16)src[e];
            }
        }
    }
}

// ---------------------------------------------------------------------------
// CSR gather mean-aggregation, in-place on the fp8 layer buffer
// ---------------------------------------------------------------------------
template<int DINP>
__global__ __launch_bounds__(256) void csr_agg_kernel(const int* __restrict__ starts,
                                                      const u16* __restrict__ csr,
                                                      u8* __restrict__ abuf) {
    constexpr int STRIDE = 2 * DINP;
    constexpr int LPR = DINP / 16;   // 4 / 8 / 16
    constexpr int EPW = 64 / LPR;    // 16 / 8 / 4
    const int wave = threadIdx.x >> 6, lane = threadIdx.x & 63;
    const int n = blockIdx.x * 4 + wave;
    if (n >= N_NODES) return;
    const int sub = lane / LPR;
    const int li = lane % LPR;
    const int s0 = starts[n], s1 = starts[n + 1];

    float acc[16] = {};
    const u8* xin = abuf + DINP;     // self half

    int e = s0 + sub;
    for (; e + EPW < s1; e += 2 * EPW) {
        int i0 = csr[e], i1 = csr[e + EPW];
        uint4 u0 = *(const uint4*)(xin + (size_t)i0 * STRIDE + li * 16);
        uint4 u1 = *(const uint4*)(xin + (size_t)i1 * STRIDE + li * 16);
        acc16fp8(acc, u0);
        acc16fp8(acc, u1);
    }
    for (; e < s1; e += EPW) {
        int i0 = csr[e];
        uint4 u0 = *(const uint4*)(xin + (size_t)i0 * STRIDE + li * 16);
        acc16fp8(acc, u0);
    }

    #pragma unroll
    for (int off = 32; off >= LPR; off >>= 1) {
        #pragma unroll
        for (int c = 0; c < 16; ++c) acc[c] += __shfl_down(acc[c], off);
    }

    if (lane < LPR) {
        float sc = 1.0f / fmaxf((float)(s1 - s0), 1.0f);
        uint4 o;
        o.x = pack4fp8(acc[0] * sc, acc[1] * sc, acc[2] * sc, acc[3] * sc);
        o.y = pack4fp8(acc[4] * sc, acc[5] * sc, acc[6] * sc, acc[7] * sc);
        o.z = pack4fp8(acc[8] * sc, acc[9] * sc, acc[10] * sc, acc[11] * sc);
        o.w = pack4fp8(acc[12] * sc, acc[13] * sc, acc[14] * sc, acc[15] * sc);
        *(uint4*)(abuf + (size_t)n * STRIDE + li * 16) = o;
    }
}

// ---------------------------------------------------------------------------
// fp8 MFMA GEMM, BK=64 K-loop (R16): half the barrier iterations of R15.
// 3-slot LDS ring of 128x64 slabs (48 KB total, 3 blocks/CU), depth-2
// prefetch with raw s_barrier + manual vmcnt.
// Chunk-XOR bank swizzle: staged global chunk = (lane&3) ^ (row&3) (the
// global side of global_load_lds is per-lane free); read inverts with
// chunk = (h*2 + lq>>1) ^ (lm&3). Enumeration: 4 dword-accesses/bank =
// wave64 floor. Epilogue: act + fp8 store (R13/R15 form).
// ---------------------------------------------------------------------------
template<int K, int NB, int ACT>
__global__ __launch_bounds__(256) void gemm_fp8_kernel(
    const u8* __restrict__ A, const u8* __restrict__ W,
    const float* __restrict__ bias,
    u8* __restrict__ out8, int gstride, int goff, int N)
{
    constexpr int NKB = K / 64;
    constexpr int MT = M_PAD / 128;          // 391 m-tiles
    constexpr int MCHUNK = (MT + 7) / 8;     // 49 per XCD
    __shared__ __align__(16) u8 As[3][128 * 64];
    __shared__ __align__(16) u8 Bs[3][128 * 64];

    const int bx = blockIdx.x;
    const int xcd = bx & 7;
    const int seq = bx >> 3;
    const int n = seq % NB;
    const int m = xcd * MCHUNK + seq / NB;
    if (m >= MT) return;
    const int bm = m * 128;
    const int bn = n * 128;

    const int tid = threadIdx.x;
    const int wave = tid >> 6, lane = tid & 63;
    const int wm = (wave & 1) * 64, wn = (wave >> 1) * 64;
    const int lm = lane & 15, lq = lane >> 4;

    // staging: wave w covers rows w*32..w*32+31; issue = 16 rows x 64 B.
    // lane -> (row = lane>>2, chunk = lane&3); global chunk XOR row&3.
    const int srow = wave * 32 + (lane >> 2);
    const int scol = (((lane & 3) ^ ((lane >> 2) & 3)) << 4);
    const u8* gA = A + (size_t)(bm + srow) * K + scol;
    const u8* gB = W + (size_t)(bn + srow) * K + scol;
    const int lbase = wave * 32 * 64;

    auto stage = [&](int s, int r) {
        const int ko = s * 64;
        load_lds16(gA + ko,                  &As[r][lbase]);
        load_lds16(gA + (size_t)16 * K + ko, &As[r][lbase + 16 * 64]);
        load_lds16(gB + ko,                  &Bs[r][lbase]);
        load_lds16(gB + (size_t)16 * K + ko, &Bs[r][lbase + 16 * 64]);
    };

    floatx4 acc[4][4] = {};

    stage(0, 0);
    if (NKB > 1) stage(1, 1);

    #pragma unroll
    for (int kb = 0; kb < NKB; ++kb) {
        if (kb + 2 < NKB) stage(kb + 2, (kb + 2) % 3);
        const int rem = NKB - 1 - kb;
        if (rem >= 2)      waitcnt_vm<8>();
        else if (rem == 1) waitcnt_vm<4>();
        else               waitcnt_vm<0>();
        raw_barrier();

        const int r = kb % 3;
        #pragma unroll
        for (int h = 0; h < 2; ++h) {
            i64 af[4], bfr[4];
            const int cA = (((h * 2 + (lq >> 1)) ^ (lm & 3)) << 4) + (lq & 1) * 8;
            #pragma unroll
            for (int mi = 0; mi < 4; ++mi)
                af[mi] = *(const i64*)&As[r][(wm + mi * 16 + lm) * 64 + cA];
            #pragma unroll
            for (int ni = 0; ni < 4; ++ni)
                bfr[ni] = *(const i64*)&Bs[r][(wn + ni * 16 + lm) * 64 + cA];
            #pragma unroll
            for (int mi = 0; mi < 4; ++mi)
                #pragma unroll
                for (int ni = 0; ni < 4; ++ni)
                    acc[mi][ni] = __builtin_amdgcn_mfma_f32_16x16x32_fp8_fp8(
                        af[mi], bfr[ni], acc[mi][ni], 0, 0, 0);
        }
        raw_barrier();
    }

    #pragma unroll
    for (int mi = 0; mi < 4; ++mi) {
        int node0 = bm + wm + mi * 16 + lq * 4;
        #pragma unroll
        for (int ni = 0; ni < 4; ++ni) {
            int o = bn + wn + ni * 16 + lm;
            float bi = bias[o];
            #pragma unroll
            for (int r = 0; r < 4; ++r) {
                int node = node0 + r;
                if (node >= N) continue;
                float v = acc[mi][ni][r] + bi;
                if (ACT == 0) v = (v > 0.0f) ? v : 0.01f * v;
                else          v = fmaxf(v, 0.0f);
                out8[(size_t)node * gstride + goff + o] = f2fp8(v);
            }
        }
    }
}

// ---------------------------------------------------------------------------
// mean pool: 2048 blocks = 512 graphs x 4 column slabs (R12). Raw sums,
// direct disjoint stores.
// ---------------------------------------------------------------------------
__global__ __launch_bounds__(256) void pool_kernel(
    const u8* __restrict__ x3, const int* __restrict__ gstart,
    float* __restrict__ pool)
{
    __shared__ float sacc[32][128];
    const int g = blockIdx.x >> 2;
    const int slab = blockIdx.x & 3;
    const int t = threadIdx.x;
    const int chain = t >> 3;
    const int li = t & 7;
    const int c0 = slab * 128 + li * 16;
    const int n0 = gstart[g], n1 = gstart[g + 1];

    float acc[16] = {};
    for (int n = n0 + chain; n < n1; n += 32) {
        uint4 u = *(const uint4*)(x3 + (size_t)n * 512 + c0);
        acc16fp8(acc, u);
    }
    #pragma unroll
    for (int j = 0; j < 16; ++j) sacc[chain][li * 16 + j] = acc[j];
    __syncthreads();
    if (t < 128) {
        float s = 0.0f;
        #pragma unroll
        for (int r = 0; r < 32; ++r) s += sacc[r][t];
        pool[(size_t)g * 512 + slab * 128 + t] = s;
    }
}

// ---------------------------------------------------------------------------
// dense head with transposed weights (R12); derives 1/cnt from gstart
// ---------------------------------------------------------------------------
__global__ __launch_bounds__(256) void dense_head_kernel(
    const float* __restrict__ pool, const int* __restrict__ gstart,
    const float* __restrict__ Wf1T, const float* __restrict__ bf1,
    const float* __restrict__ Wf2T, const float* __restrict__ bf2,
    const float* __restrict__ Wo,  const float* __restrict__ bo,
    float* __restrict__ out)
{
    __shared__ float sp[512];
    __shared__ float s4[256];
    __shared__ float red[128];
    const int g = blockIdx.x;
    const int t = threadIdx.x;
    const float sc = 1.0f / fmaxf((float)(gstart[g + 1] - gstart[g]), 1.0f);

    sp[t]       = pool[(size_t)g * 512 + t] * sc;
    sp[t + 256] = pool[(size_t)g * 512 + 256 + t] * sc;
    __syncthreads();

    {
        float s = bf1[t];
        #pragma unroll 8
        for (int k = 0; k < 512; ++k) s += sp[k] * Wf1T[(size_t)k * 256 + t];
        s4[t] = fmaxf(s, 0.0f);
    }
    __syncthreads();
    if (t < 128) {
        float s = bf2[t];
        #pragma unroll 8
        for (int k = 0; k < 256; ++k) s += s4[k] * Wf2T[(size_t)k * 128 + t];
        red[t] = fmaxf(s, 0.0f) * Wo[t];
    }
    __syncthreads();
    for (int off = 64; off >= 1; off >>= 1) {
        if (t < off) red[t] += red[t + off];
        __syncthreads();
    }
    if (t == 0) out[g] = 1.0f / (1.0f + expf(-(red[0] + bo[0])));
}

// ---------------------------------------------------------------------------
extern "C" void kernel_launch(void* const* d_in, const int* in_sizes, int n_in,
                              void* d_out, int out_size, void* d_ws, size_t ws_size,
                              hipStream_t stream)
{
    const float* x     = (const float*)d_in[0];
    const int*   ei    = (const int*)  d_in[1];
    const int*   batch = (const int*)  d_in[2];
    const float* Wl1   = (const float*)d_in[3];
    const float* bl1   = (const float*)d_in[4];
    const float* Wr1   = (const float*)d_in[5];
    const float* Wl2   = (const float*)d_in[6];
    const float* bl2   = (const float*)d_in[7];
    const float* Wr2   = (const float*)d_in[8];
    const float* Wl3   = (const float*)d_in[9];
    const float* bl3   = (const float*)d_in[10];
    const float* Wr3   = (const float*)d_in[11];
    const float* Wf1   = (const float*)d_in[12];
    const float* bf1   = (const float*)d_in[13];
    const float* Wf2   = (const float*)d_in[14];
    const float* bf2   = (const float*)d_in[15];
    const float* Wo    = (const float*)d_in[16];
    const float* bo    = (const float*)d_in[17];

    const int* src = ei;
    const int* dst = ei + N_EDGES;

    // ---- workspace layout ----
    char* p = (char*)d_ws;
    auto alloc = [&](size_t bytes) { char* r = p; p += (bytes + 255) & ~(size_t)255; return r; };
    int*   gstart = (int*)  alloc(513 * 4);
    float* pool   = (float*)alloc((size_t)512 * 512 * 4);
    float* Wf1T   = (float*)alloc((size_t)512 * 256 * 4);
    float* Wf2T   = (float*)alloc((size_t)256 * 128 * 4);
    u8*    abuf1  = (u8*)   alloc((size_t)M_PAD * 128);
    u8*    abuf2  = (u8*)   alloc((size_t)M_PAD * 256);
    u8*    abuf3  = (u8*)   alloc((size_t)M_PAD * 512);
    u8*    x3buf8 = (u8*)   alloc((size_t)M_PAD * 512);
    u8*    wb1    = (u8*)   alloc((size_t)128 * 128);
    u8*    wb2    = (u8*)   alloc((size_t)256 * 256);
    u8*    wb3    = (u8*)   alloc((size_t)512 * 512);
    int*   degi   = (int*)  alloc(50176 * 4);   // memset target
    int*   cursor = (int*)  alloc(50176 * 4);   // zeroed in scan_all
    int*   starts = (int*)  alloc(50432 * 4);
    u16*   csr    = (u16*)  alloc((size_t)N_EDGES * 2);

    // ---- CSR build + conversions ----
    hipMemsetAsync(degi, 0, 50176 * 4, stream);
    const int CONV_N = N_NODES * 16 + 128 * 64 + 256 * 128 + 512 * 256
                     + 256 * 512 + 128 * 256;
    const int CONV_BLOCKS = (CONV_N + 255) / 256;
    prep_kernel<<<COUNT_BLOCKS + CONV_BLOCKS, 256, 0, stream>>>(
        dst, degi, x, Wl1, Wr1, Wl2, Wr2, Wl3, Wr3, Wf1, Wf2,
        abuf1, wb1, wb2, wb3, Wf1T, Wf2T);
    scan_all_kernel<<<1, 1024, 0, stream>>>(degi, starts, batch, gstart, cursor);
    fill_seg_kernel<<<SEG_BLOCKS * 8, 256, 0, stream>>>(src, dst, starts, cursor, csr);

    const int GB = 12500;
    const int GEMM_GRID = 49 * 8;

    // ---- layer 1: 50 -> 128, leaky_relu ----
    csr_agg_kernel<64><<<GB, 256, 0, stream>>>(starts, csr, abuf1);
    gemm_fp8_kernel<128, 1, 0><<<GEMM_GRID * 1, 256, 0, stream>>>(
        abuf1, wb1, bl1, abuf2, 256, 128, N_NODES);

    // ---- layer 2: 128 -> 256, relu ----
    csr_agg_kernel<128><<<GB, 256, 0, stream>>>(starts, csr, abuf2);
    gemm_fp8_kernel<256, 2, 1><<<GEMM_GRID * 2, 256, 0, stream>>>(
        abuf2, wb2, bl2, abuf3, 512, 256, N_NODES);

    // ---- layer 3: 256 -> 512, relu -> x3 fp8 ----
    csr_agg_kernel<256><<<GB, 256, 0, stream>>>(starts, csr, abuf3);
    gemm_fp8_kernel<512, 4, 1><<<GEMM_GRID * 4, 256, 0, stream>>>(
        abuf3, wb3, bl3, x3buf8, 512, 0, N_NODES);

    // ---- pool + dense head ----
    pool_kernel<<<N_GRAPHS * 4, 256, 0, stream>>>(x3buf8, gstart, pool);
    dense_head_kernel<<<N_GRAPHS, 256, 0, stream>>>(
        pool, gstart, Wf1T, bf1, Wf2T, bf2, Wo, bo, (float*)d_out);
}

// Round 17
// 390.311 us; speedup vs baseline: 1.3389x; 1.3389x over previous
//
#include <hip/hip_runtime.h>
#include <math.h>

#define N_NODES 50000
#define N_EDGES 800000
#define N_GRAPHS 512
#define M_PAD 50048   // N_NODES rounded up to 128
#define SEG_SZ 6250   // N_NODES / 8 (per-XCD dst segment)
#define EPT 8         // edges per thread per count/fill block
#define SEG_BLOCKS 391            // ceil(N_EDGES / (256*EPT))
#define COUNT_BLOCKS (SEG_BLOCKS * 8)

typedef unsigned char u8;
typedef unsigned short u16;
typedef unsigned int u32;
typedef long i64;
using floatx4 = __attribute__((ext_vector_type(4))) float;
using floatx2 = __attribute__((ext_vector_type(2))) float;

// f32 -> OCP e4m3 (single byte via HW pack)
__device__ __forceinline__ u8 f2fp8(float v) {
    return (u8)(__builtin_amdgcn_cvt_pk_fp8_f32(v, v, 0, false) & 0xFF);
}
__device__ __forceinline__ u32 pack4fp8(float a, float b, float c, float d) {
    u32 p = __builtin_amdgcn_cvt_pk_fp8_f32(a, b, 0, false);
    return __builtin_amdgcn_cvt_pk_fp8_f32(c, d, p, true);
}
// accumulate 16 fp8 (one uint4) into acc[16]
__device__ __forceinline__ void acc16fp8(float* acc, uint4 u) {
    const u32 w[4] = {u.x, u.y, u.z, u.w};
    #pragma unroll
    for (int j = 0; j < 4; ++j) {
        floatx2 lo = __builtin_amdgcn_cvt_pk_f32_fp8((int)w[j], false);
        floatx2 hi = __builtin_amdgcn_cvt_pk_f32_fp8((int)w[j], true);
        acc[j * 4 + 0] += lo[0]; acc[j * 4 + 1] += lo[1];
        acc[j * 4 + 2] += hi[0]; acc[j * 4 + 3] += hi[1];
    }
}

// async global->LDS, 16 B per lane; LDS dest = base + lane*16 (wave-uniform base)
__device__ __forceinline__ void load_lds16(const u8* g, u8* l) {
    __builtin_amdgcn_global_load_lds(
        (const __attribute__((address_space(1))) u32*)g,
        (__attribute__((address_space(3))) u32*)l, 16, 0, 0);
}
template<int N> __device__ __forceinline__ void waitcnt_vm() {
    __builtin_amdgcn_s_waitcnt(0x0F70 | N);
}
__device__ __forceinline__ void raw_barrier() {
    asm volatile("s_barrier" ::: "memory");
}

// ---------------------------------------------------------------------------
// prep kernel: XCD-partitioned degree count (blocks 0..COUNT_BLOCKS) +
// all dtype conversions (remaining blocks) — independent work, one launch.
// ---------------------------------------------------------------------------
__global__ __launch_bounds__(256) void prep_kernel(
    const int* __restrict__ dst, int* __restrict__ degi,
    const float* __restrict__ x,
    const float* __restrict__ Wl1, const float* __restrict__ Wr1,
    const float* __restrict__ Wl2, const float* __restrict__ Wr2,
    const float* __restrict__ Wl3, const float* __restrict__ Wr3,
    const float* __restrict__ Wf1, const float* __restrict__ Wf2,
    u8* __restrict__ abuf1,
    u8* __restrict__ wb1, u8* __restrict__ wb2, u8* __restrict__ wb3,
    float* __restrict__ Wf1T, float* __restrict__ Wf2T)
{
    if (blockIdx.x < COUNT_BLOCKS) {
        const int bx = blockIdx.x;
        const int seg = bx & 7;
        const int lo = seg * SEG_SZ, hi = lo + SEG_SZ;
        int e = (bx >> 3) * (256 * EPT) + threadIdx.x;
        #pragma unroll
        for (int j = 0; j < EPT; ++j, e += 256) {
            if (e < N_EDGES) {
                int d = dst[e];
                if (d >= lo && d < hi) atomicAdd(&degi[d], 1);
            }
        }
        return;
    }
    int i = (blockIdx.x - COUNT_BLOCKS) * 256 + threadIdx.x;
    if (i < N_NODES * 16) {
        int n = i >> 4, c = (i & 15) * 4;
        float v[4];
        #pragma unroll
        for (int j = 0; j < 4; ++j) {
            int cc = c + j;
            v[j] = (cc < 50) ? x[n * 50 + cc] : 0.0f;
        }
        *(u32*)(abuf1 + (size_t)n * 128 + 64 + c) = pack4fp8(v[0], v[1], v[2], v[3]);
        return;
    }
    i -= N_NODES * 16;
    if (i < 128 * 64) {
        int o = i / 64, c = i % 64;
        float vl = (c < 50) ? Wl1[o * 50 + c] : 0.0f;
        float vr = (c < 50) ? Wr1[o * 50 + c] : 0.0f;
        wb1[(size_t)o * 128 + c] = f2fp8(vl);
        wb1[(size_t)o * 128 + 64 + c] = f2fp8(vr);
        return;
    }
    i -= 128 * 64;
    if (i < 256 * 128) {
        int o = i / 128, c = i % 128;
        wb2[(size_t)o * 256 + c] = f2fp8(Wl2[o * 128 + c]);
        wb2[(size_t)o * 256 + 128 + c] = f2fp8(Wr2[o * 128 + c]);
        return;
    }
    i -= 256 * 128;
    if (i < 512 * 256) {
        int o = i / 256, c = i % 256;
        wb3[(size_t)o * 512 + c] = f2fp8(Wl3[o * 256 + c]);
        wb3[(size_t)o * 512 + 256 + c] = f2fp8(Wr3[o * 256 + c]);
        return;
    }
    i -= 512 * 256;
    if (i < 256 * 512) {   // Wf1T[k][o] = Wf1[o][k]
        int o = i >> 9, k = i & 511;
        Wf1T[(size_t)k * 256 + o] = Wf1[(size_t)o * 512 + k];
        return;
    }
    i -= 256 * 512;
    if (i < 128 * 256) {   // Wf2T[k][o] = Wf2[o][k]
        int o = i >> 8, k = i & 255;
        Wf2T[(size_t)k * 128 + o] = Wf2[(size_t)o * 256 + k];
    }
}

// ---------------------------------------------------------------------------
// multi-block scan (R15 form — parallel, cheap)
// ---------------------------------------------------------------------------
__global__ void scan1_kernel(const int* __restrict__ degi, int* __restrict__ starts,
                             int* __restrict__ bsum) {
    __shared__ int s[256];
    int t = threadIdx.x, i = blockIdx.x * 256 + t;
    int v = (i < N_NODES) ? degi[i] : 0;
    s[t] = v; __syncthreads();
    for (int off = 1; off < 256; off <<= 1) {
        int x = (t >= off) ? s[t - off] : 0;
        __syncthreads();
        s[t] += x;
        __syncthreads();
    }
    if (i < N_NODES) starts[i] = s[t] - v;
    if (t == 255) bsum[blockIdx.x] = s[255];
}

__global__ void scan2_kernel(const int* __restrict__ bsum, int* __restrict__ boff,
                             int* __restrict__ starts, int nb) {
    __shared__ int s[256];
    int t = threadIdx.x;
    int v = (t < nb) ? bsum[t] : 0;
    s[t] = v; __syncthreads();
    for (int off = 1; off < 256; off <<= 1) {
        int x = (t >= off) ? s[t - off] : 0;
        __syncthreads();
        s[t] += x;
        __syncthreads();
    }
    if (t < nb) boff[t] = s[t] - v;
    if (t == nb - 1) starts[N_NODES] = s[t];
}

// scan3 + gstart merged (both are 196-block sweeps over nodes)
__global__ void scan3_gstart_kernel(int* __restrict__ starts, const int* __restrict__ boff,
                                    const int* __restrict__ batch, int* __restrict__ gstart) {
    int i = blockIdx.x * 256 + threadIdx.x;
    if (i >= N_NODES) return;
    starts[i] += boff[blockIdx.x];
    int b = batch[i];
    int bp = (i == 0) ? -1 : batch[i - 1];
    for (int g = bp + 1; g <= b; ++g) gstart[g] = i;
    if (i == N_NODES - 1)
        for (int g = b + 1; g <= N_GRAPHS; ++g) gstart[g] = N_NODES;
}

// ---------------------------------------------------------------------------
// CSR fill — XCD-partitioned (R9, confirmed win)
// ---------------------------------------------------------------------------
__global__ __launch_bounds__(256) void fill_seg_kernel(const int* __restrict__ src,
                                                       const int* __restrict__ dst,
                                                       const int* __restrict__ starts,
                                                       int* __restrict__ cursor,
                                                       u16* __restrict__ csr) {
    const int seg = blockIdx.x & 7;
    const int lo = seg * SEG_SZ, hi = lo + SEG_SZ;
    int e = (blockIdx.x >> 3) * (256 * EPT) + threadIdx.x;
    #pragma unroll
    for (int j = 0; j < EPT; ++j, e += 256) {
        if (e < N_EDGES) {
            int d = dst[e];
            if (d >= lo && d < hi) {
                int p = atomicAdd(&cursor[d], 1);
                csr[starts[d] + p] = (u16)src[e];
            }
        }
    }
}

// ---------------------------------------------------------------------------
// CSR gather mean-aggregation, in-place on the fp8 layer buffer
// ---------------------------------------------------------------------------
template<int DINP>
__global__ __launch_bounds__(256) void csr_agg_kernel(const int* __restrict__ starts,
                                                      const u16* __restrict__ csr,
                                                      u8* __restrict__ abuf) {
    constexpr int STRIDE = 2 * DINP;
    constexpr int LPR = DINP / 16;   // 4 / 8 / 16
    constexpr int EPW = 64 / LPR;    // 16 / 8 / 4
    const int wave = threadIdx.x >> 6, lane = threadIdx.x & 63;
    const int n = blockIdx.x * 4 + wave;
    if (n >= N_NODES) return;
    const int sub = lane / LPR;
    const int li = lane % LPR;
    const int s0 = starts[n], s1 = starts[n + 1];

    float acc[16] = {};
    const u8* xin = abuf + DINP;     // self half

    int e = s0 + sub;
    for (; e + EPW < s1; e += 2 * EPW) {
        int i0 = csr[e], i1 = csr[e + EPW];
        uint4 u0 = *(const uint4*)(xin + (size_t)i0 * STRIDE + li * 16);
        uint4 u1 = *(const uint4*)(xin + (size_t)i1 * STRIDE + li * 16);
        acc16fp8(acc, u0);
        acc16fp8(acc, u1);
    }
    for (; e < s1; e += EPW) {
        int i0 = csr[e];
        uint4 u0 = *(const uint4*)(xin + (size_t)i0 * STRIDE + li * 16);
        acc16fp8(acc, u0);
    }

    #pragma unroll
    for (int off = 32; off >= LPR; off >>= 1) {
        #pragma unroll
        for (int c = 0; c < 16; ++c) acc[c] += __shfl_down(acc[c], off);
    }

    if (lane < LPR) {
        float sc = 1.0f / fmaxf((float)(s1 - s0), 1.0f);
        uint4 o;
        o.x = pack4fp8(acc[0] * sc, acc[1] * sc, acc[2] * sc, acc[3] * sc);
        o.y = pack4fp8(acc[4] * sc, acc[5] * sc, acc[6] * sc, acc[7] * sc);
        o.z = pack4fp8(acc[8] * sc, acc[9] * sc, acc[10] * sc, acc[11] * sc);
        o.w = pack4fp8(acc[12] * sc, acc[13] * sc, acc[14] * sc, acc[15] * sc);
        *(uint4*)(abuf + (size_t)n * STRIDE + li * 16) = o;
    }
}

// ---------------------------------------------------------------------------
// fp8 MFMA GEMM, BK=64 K-loop with chunk-XOR bank swizzle (R16 core)
// ---------------------------------------------------------------------------
template<int K, int NB, int ACT>
__global__ __launch_bounds__(256) void gemm_fp8_kernel(
    const u8* __restrict__ A, const u8* __restrict__ W,
    const float* __restrict__ bias,
    u8* __restrict__ out8, int gstride, int goff, int N)
{
    constexpr int NKB = K / 64;
    constexpr int MT = M_PAD / 128;          // 391 m-tiles
    constexpr int MCHUNK = (MT + 7) / 8;     // 49 per XCD
    __shared__ __align__(16) u8 As[3][128 * 64];
    __shared__ __align__(16) u8 Bs[3][128 * 64];

    const int bx = blockIdx.x;
    const int xcd = bx & 7;
    const int seq = bx >> 3;
    const int n = seq % NB;
    const int m = xcd * MCHUNK + seq / NB;
    if (m >= MT) return;
    const int bm = m * 128;
    const int bn = n * 128;

    const int tid = threadIdx.x;
    const int wave = tid >> 6, lane = tid & 63;
    const int wm = (wave & 1) * 64, wn = (wave >> 1) * 64;
    const int lm = lane & 15, lq = lane >> 4;

    const int srow = wave * 32 + (lane >> 2);
    const int scol = (((lane & 3) ^ ((lane >> 2) & 3)) << 4);
    const u8* gA = A + (size_t)(bm + srow) * K + scol;
    const u8* gB = W + (size_t)(bn + srow) * K + scol;
    const int lbase = wave * 32 * 64;

    auto stage = [&](int s, int r) {
        const int ko = s * 64;
        load_lds16(gA + ko,                  &As[r][lbase]);
        load_lds16(gA + (size_t)16 * K + ko, &As[r][lbase + 16 * 64]);
        load_lds16(gB + ko,                  &Bs[r][lbase]);
        load_lds16(gB + (size_t)16 * K + ko, &Bs[r][lbase + 16 * 64]);
    };

    floatx4 acc[4][4] = {};

    stage(0, 0);
    if (NKB > 1) stage(1, 1);

    #pragma unroll
    for (int kb = 0; kb < NKB; ++kb) {
        if (kb + 2 < NKB) stage(kb + 2, (kb + 2) % 3);
        const int rem = NKB - 1 - kb;
        if (rem >= 2)      waitcnt_vm<8>();
        else if (rem == 1) waitcnt_vm<4>();
        else               waitcnt_vm<0>();
        raw_barrier();

        const int r = kb % 3;
        #pragma unroll
        for (int h = 0; h < 2; ++h) {
            i64 af[4], bfr[4];
            const int cA = (((h * 2 + (lq >> 1)) ^ (lm & 3)) << 4) + (lq & 1) * 8;
            #pragma unroll
            for (int mi = 0; mi < 4; ++mi)
                af[mi] = *(const i64*)&As[r][(wm + mi * 16 + lm) * 64 + cA];
            #pragma unroll
            for (int ni = 0; ni < 4; ++ni)
                bfr[ni] = *(const i64*)&Bs[r][(wn + ni * 16 + lm) * 64 + cA];
            #pragma unroll
            for (int mi = 0; mi < 4; ++mi)
                #pragma unroll
                for (int ni = 0; ni < 4; ++ni)
                    acc[mi][ni] = __builtin_amdgcn_mfma_f32_16x16x32_fp8_fp8(
                        af[mi], bfr[ni], acc[mi][ni], 0, 0, 0);
        }
        raw_barrier();
    }

    #pragma unroll
    for (int mi = 0; mi < 4; ++mi) {
        int node0 = bm + wm + mi * 16 + lq * 4;
        #pragma unroll
        for (int ni = 0; ni < 4; ++ni) {
            int o = bn + wn + ni * 16 + lm;
            float bi = bias[o];
            #pragma unroll
            for (int r = 0; r < 4; ++r) {
                int node = node0 + r;
                if (node >= N) continue;
                float v = acc[mi][ni][r] + bi;
                if (ACT == 0) v = (v > 0.0f) ? v : 0.01f * v;
                else          v = fmaxf(v, 0.0f);
                out8[(size_t)node * gstride + goff + o] = f2fp8(v);
            }
        }
    }
}

// ---------------------------------------------------------------------------
// mean pool: 2048 blocks = 512 graphs x 4 column slabs (R12). Raw sums,
// direct disjoint stores.
// ---------------------------------------------------------------------------
__global__ __launch_bounds__(256) void pool_kernel(
    const u8* __restrict__ x3, const int* __restrict__ gstart,
    float* __restrict__ pool)
{
    __shared__ float sacc[32][128];
    const int g = blockIdx.x >> 2;
    const int slab = blockIdx.x & 3;
    const int t = threadIdx.x;
    const int chain = t >> 3;
    const int li = t & 7;
    const int c0 = slab * 128 + li * 16;
    const int n0 = gstart[g], n1 = gstart[g + 1];

    float acc[16] = {};
    for (int n = n0 + chain; n < n1; n += 32) {
        uint4 u = *(const uint4*)(x3 + (size_t)n * 512 + c0);
        acc16fp8(acc, u);
    }
    #pragma unroll
    for (int j = 0; j < 16; ++j) sacc[chain][li * 16 + j] = acc[j];
    __syncthreads();
    if (t < 128) {
        float s = 0.0f;
        #pragma unroll
        for (int r = 0; r < 32; ++r) s += sacc[r][t];
        pool[(size_t)g * 512 + slab * 128 + t] = s;
    }
}

// ---------------------------------------------------------------------------
// dense head with transposed weights (R12); derives 1/cnt from gstart
// ---------------------------------------------------------------------------
__global__ __launch_bounds__(256) void dense_head_kernel(
    const float* __restrict__ pool, const int* __restrict__ gstart,
    const float* __restrict__ Wf1T, const float* __restrict__ bf1,
    const float* __restrict__ Wf2T, const float* __restrict__ bf2,
    const float* __restrict__ Wo,  const float* __restrict__ bo,
    float* __restrict__ out)
{
    __shared__ float sp[512];
    __shared__ float s4[256];
    __shared__ float red[128];
    const int g = blockIdx.x;
    const int t = threadIdx.x;
    const float sc = 1.0f / fmaxf((float)(gstart[g + 1] - gstart[g]), 1.0f);

    sp[t]       = pool[(size_t)g * 512 + t] * sc;
    sp[t + 256] = pool[(size_t)g * 512 + 256 + t] * sc;
    __syncthreads();

    {
        float s = bf1[t];
        #pragma unroll 8
        for (int k = 0; k < 512; ++k) s += sp[k] * Wf1T[(size_t)k * 256 + t];
        s4[t] = fmaxf(s, 0.0f);
    }
    __syncthreads();
    if (t < 128) {
        float s = bf2[t];
        #pragma unroll 8
        for (int k = 0; k < 256; ++k) s += s4[k] * Wf2T[(size_t)k * 128 + t];
        red[t] = fmaxf(s, 0.0f) * Wo[t];
    }
    __syncthreads();
    for (int off = 64; off >= 1; off >>= 1) {
        if (t < off) red[t] += red[t + off];
        __syncthreads();
    }
    if (t == 0) out[g] = 1.0f / (1.0f + expf(-(red[0] + bo[0])));
}

// ---------------------------------------------------------------------------
extern "C" void kernel_launch(void* const* d_in, const int* in_sizes, int n_in,
                              void* d_out, int out_size, void* d_ws, size_t ws_size,
                              hipStream_t stream)
{
    const float* x     = (const float*)d_in[0];
    const int*   ei    = (const int*)  d_in[1];
    const int*   batch = (const int*)  d_in[2];
    const float* Wl1   = (const float*)d_in[3];
    const float* bl1   = (const float*)d_in[4];
    const float* Wr1   = (const float*)d_in[5];
    const float* Wl2   = (const float*)d_in[6];
    const float* bl2   = (const float*)d_in[7];
    const float* Wr2   = (const float*)d_in[8];
    const float* Wl3   = (const float*)d_in[9];
    const float* bl3   = (const float*)d_in[10];
    const float* Wr3   = (const float*)d_in[11];
    const float* Wf1   = (const float*)d_in[12];
    const float* bf1   = (const float*)d_in[13];
    const float* Wf2   = (const float*)d_in[14];
    const float* bf2   = (const float*)d_in[15];
    const float* Wo    = (const float*)d_in[16];
    const float* bo    = (const float*)d_in[17];

    const int* src = ei;
    const int* dst = ei + N_EDGES;

    // ---- workspace layout ----
    char* p = (char*)d_ws;
    auto alloc = [&](size_t bytes) { char* r = p; p += (bytes + 255) & ~(size_t)255; return r; };
    int*   gstart = (int*)  alloc(513 * 4);
    float* pool   = (float*)alloc((size_t)512 * 512 * 4);
    float* Wf1T   = (float*)alloc((size_t)512 * 256 * 4);
    float* Wf2T   = (float*)alloc((size_t)256 * 128 * 4);
    u8*    abuf1  = (u8*)   alloc((size_t)M_PAD * 128);
    u8*    abuf2  = (u8*)   alloc((size_t)M_PAD * 256);
    u8*    abuf3  = (u8*)   alloc((size_t)M_PAD * 512);
    u8*    x3buf8 = (u8*)   alloc((size_t)M_PAD * 512);
    u8*    wb1    = (u8*)   alloc((size_t)128 * 128);
    u8*    wb2    = (u8*)   alloc((size_t)256 * 256);
    u8*    wb3    = (u8*)   alloc((size_t)512 * 512);
    // zero-init block: degi + cursor (one memset)
    char*  zbase  = p;
    int*   degi   = (int*)  alloc(50176 * 4);
    int*   cursor = (int*)  alloc(50176 * 4);
    size_t zbytes = (size_t)(p - zbase);
    int*   starts = (int*)  alloc(50432 * 4);
    int*   bsum   = (int*)  alloc(256 * 4);
    int*   boff   = (int*)  alloc(256 * 4);
    u16*   csr    = (u16*)  alloc((size_t)N_EDGES * 2);

    // ---- CSR build + conversions ----
    hipMemsetAsync(zbase, 0, zbytes, stream);
    const int CONV_N = N_NODES * 16 + 128 * 64 + 256 * 128 + 512 * 256
                     + 256 * 512 + 128 * 256;
    const int CONV_BLOCKS = (CONV_N + 255) / 256;
    prep_kernel<<<COUNT_BLOCKS + CONV_BLOCKS, 256, 0, stream>>>(
        dst, degi, x, Wl1, Wr1, Wl2, Wr2, Wl3, Wr3, Wf1, Wf2,
        abuf1, wb1, wb2, wb3, Wf1T, Wf2T);
    scan1_kernel<<<196, 256, 0, stream>>>(degi, starts, bsum);
    scan2_kernel<<<1, 256, 0, stream>>>(bsum, boff, starts, 196);
    scan3_gstart_kernel<<<196, 256, 0, stream>>>(starts, boff, batch, gstart);
    fill_seg_kernel<<<SEG_BLOCKS * 8, 256, 0, stream>>>(src, dst, starts, cursor, csr);

    const int GB = 12500;
    const int GEMM_GRID = 49 * 8;

    // ---- layer 1: 50 -> 128, leaky_relu ----
    csr_agg_kernel<64><<<GB, 256, 0, stream>>>(starts, csr, abuf1);
    gemm_fp8_kernel<128, 1, 0><<<GEMM_GRID * 1, 256, 0, stream>>>(
        abuf1, wb1, bl1, abuf2, 256, 128, N_NODES);

    // ---- layer 2: 128 -> 256, relu ----
    csr_agg_kernel<128><<<GB, 256, 0, stream>>>(starts, csr, abuf2);
    gemm_fp8_kernel<256, 2, 1><<<GEMM_GRID * 2, 256, 0, stream>>>(
        abuf2, wb2, bl2, abuf3, 512, 256, N_NODES);

    // ---- layer 3: 256 -> 512, relu -> x3 fp8 ----
    csr_agg_kernel<256><<<GB, 256, 0, stream>>>(starts, csr, abuf3);
    gemm_fp8_kernel<512, 4, 1><<<GEMM_GRID * 4, 256, 0, stream>>>(
        abuf3, wb3, bl3, x3buf8, 512, 0, N_NODES);

    // ---- pool + dense head ----
    pool_kernel<<<N_GRAPHS * 4, 256, 0, stream>>>(x3buf8, gstart, pool);
    dense_head_kernel<<<N_GRAPHS, 256, 0, stream>>>(
        pool, gstart, Wf1T, bf1, Wf2T, bf2, Wo, bo, (float*)d_out);
}

// Round 18
// 373.388 us; speedup vs baseline: 1.3995x; 1.0453x over previous
//
#include <hip/hip_runtime.h>
#include <math.h>

#define N_NODES 50000
#define N_EDGES 800000
#define N_GRAPHS 512
#define M_PAD 50048   // N_NODES rounded up to 128
#define SEG_SZ 6250   // N_NODES / 8 (per-XCD dst segment)
#define EPT 8         // edges per thread per count/fill block
#define SEG_BLOCKS 391            // ceil(N_EDGES / (256*EPT))
#define COUNT_BLOCKS (SEG_BLOCKS * 8)

typedef unsigned char u8;
typedef unsigned short u16;
typedef unsigned int u32;
typedef long i64;
using floatx4 = __attribute__((ext_vector_type(4))) float;
using floatx2 = __attribute__((ext_vector_type(2))) float;

// f32 -> OCP e4m3 (single byte via HW pack)
__device__ __forceinline__ u8 f2fp8(float v) {
    return (u8)(__builtin_amdgcn_cvt_pk_fp8_f32(v, v, 0, false) & 0xFF);
}
__device__ __forceinline__ u32 pack4fp8(float a, float b, float c, float d) {
    u32 p = __builtin_amdgcn_cvt_pk_fp8_f32(a, b, 0, false);
    return __builtin_amdgcn_cvt_pk_fp8_f32(c, d, p, true);
}
// accumulate 16 fp8 (one uint4) into acc[16]
__device__ __forceinline__ void acc16fp8(float* acc, uint4 u) {
    const u32 w[4] = {u.x, u.y, u.z, u.w};
    #pragma unroll
    for (int j = 0; j < 4; ++j) {
        floatx2 lo = __builtin_amdgcn_cvt_pk_f32_fp8((int)w[j], false);
        floatx2 hi = __builtin_amdgcn_cvt_pk_f32_fp8((int)w[j], true);
        acc[j * 4 + 0] += lo[0]; acc[j * 4 + 1] += lo[1];
        acc[j * 4 + 2] += hi[0]; acc[j * 4 + 3] += hi[1];
    }
}

// async global->LDS, 16 B per lane; LDS dest = base + lane*16 (wave-uniform base)
__device__ __forceinline__ void load_lds16(const u8* g, u8* l) {
    __builtin_amdgcn_global_load_lds(
        (const __attribute__((address_space(1))) u32*)g,
        (__attribute__((address_space(3))) u32*)l, 16, 0, 0);
}
template<int N> __device__ __forceinline__ void waitcnt_vm() {
    __builtin_amdgcn_s_waitcnt(0x0F70 | N);
}
__device__ __forceinline__ void raw_barrier() {
    asm volatile("s_barrier" ::: "memory");
}

// ---------------------------------------------------------------------------
// prep kernel: XCD-partitioned degree count + all dtype conversions
// ---------------------------------------------------------------------------
__global__ __launch_bounds__(256) void prep_kernel(
    const int* __restrict__ dst, int* __restrict__ degi,
    const float* __restrict__ x,
    const float* __restrict__ Wl1, const float* __restrict__ Wr1,
    const float* __restrict__ Wl2, const float* __restrict__ Wr2,
    const float* __restrict__ Wl3, const float* __restrict__ Wr3,
    const float* __restrict__ Wf1, const float* __restrict__ Wf2,
    u8* __restrict__ abuf1,
    u8* __restrict__ wb1, u8* __restrict__ wb2, u8* __restrict__ wb3,
    float* __restrict__ Wf1T, float* __restrict__ Wf2T)
{
    if (blockIdx.x < COUNT_BLOCKS) {
        const int bx = blockIdx.x;
        const int seg = bx & 7;
        const int lo = seg * SEG_SZ, hi = lo + SEG_SZ;
        int e = (bx >> 3) * (256 * EPT) + threadIdx.x;
        #pragma unroll
        for (int j = 0; j < EPT; ++j, e += 256) {
            if (e < N_EDGES) {
                int d = dst[e];
                if (d >= lo && d < hi) atomicAdd(&degi[d], 1);
            }
        }
        return;
    }
    int i = (blockIdx.x - COUNT_BLOCKS) * 256 + threadIdx.x;
    if (i < N_NODES * 16) {
        int n = i >> 4, c = (i & 15) * 4;
        float v[4];
        #pragma unroll
        for (int j = 0; j < 4; ++j) {
            int cc = c + j;
            v[j] = (cc < 50) ? x[n * 50 + cc] : 0.0f;
        }
        *(u32*)(abuf1 + (size_t)n * 128 + 64 + c) = pack4fp8(v[0], v[1], v[2], v[3]);
        return;
    }
    i -= N_NODES * 16;
    if (i < 128 * 64) {
        int o = i / 64, c = i % 64;
        float vl = (c < 50) ? Wl1[o * 50 + c] : 0.0f;
        float vr = (c < 50) ? Wr1[o * 50 + c] : 0.0f;
        wb1[(size_t)o * 128 + c] = f2fp8(vl);
        wb1[(size_t)o * 128 + 64 + c] = f2fp8(vr);
        return;
    }
    i -= 128 * 64;
    if (i < 256 * 128) {
        int o = i / 128, c = i % 128;
        wb2[(size_t)o * 256 + c] = f2fp8(Wl2[o * 128 + c]);
        wb2[(size_t)o * 256 + 128 + c] = f2fp8(Wr2[o * 128 + c]);
        return;
    }
    i -= 256 * 128;
    if (i < 512 * 256) {
        int o = i / 256, c = i % 256;
        wb3[(size_t)o * 512 + c] = f2fp8(Wl3[o * 256 + c]);
        wb3[(size_t)o * 512 + 256 + c] = f2fp8(Wr3[o * 256 + c]);
        return;
    }
    i -= 512 * 256;
    if (i < 256 * 512) {   // Wf1T[k][o] = Wf1[o][k]
        int o = i >> 9, k = i & 511;
        Wf1T[(size_t)k * 256 + o] = Wf1[(size_t)o * 512 + k];
        return;
    }
    i -= 256 * 512;
    if (i < 128 * 256) {   // Wf2T[k][o] = Wf2[o][k]
        int o = i >> 8, k = i & 255;
        Wf2T[(size_t)k * 128 + o] = Wf2[(size_t)o * 256 + k];
    }
}

// ---------------------------------------------------------------------------
// multi-block scan (R15 form — parallel, cheap)
// ---------------------------------------------------------------------------
__global__ void scan1_kernel(const int* __restrict__ degi, int* __restrict__ starts,
                             int* __restrict__ bsum) {
    __shared__ int s[256];
    int t = threadIdx.x, i = blockIdx.x * 256 + t;
    int v = (i < N_NODES) ? degi[i] : 0;
    s[t] = v; __syncthreads();
    for (int off = 1; off < 256; off <<= 1) {
        int x = (t >= off) ? s[t - off] : 0;
        __syncthreads();
        s[t] += x;
        __syncthreads();
    }
    if (i < N_NODES) starts[i] = s[t] - v;
    if (t == 255) bsum[blockIdx.x] = s[255];
}

__global__ void scan2_kernel(const int* __restrict__ bsum, int* __restrict__ boff,
                             int* __restrict__ starts, int nb) {
    __shared__ int s[256];
    int t = threadIdx.x;
    int v = (t < nb) ? bsum[t] : 0;
    s[t] = v; __syncthreads();
    for (int off = 1; off < 256; off <<= 1) {
        int x = (t >= off) ? s[t - off] : 0;
        __syncthreads();
        s[t] += x;
        __syncthreads();
    }
    if (t < nb) boff[t] = s[t] - v;
    if (t == nb - 1) starts[N_NODES] = s[t];
}

// scan3 + gstart merged (both are 196-block sweeps over nodes)
__global__ void scan3_gstart_kernel(int* __restrict__ starts, const int* __restrict__ boff,
                                    const int* __restrict__ batch, int* __restrict__ gstart) {
    int i = blockIdx.x * 256 + threadIdx.x;
    if (i >= N_NODES) return;
    starts[i] += boff[blockIdx.x];
    int b = batch[i];
    int bp = (i == 0) ? -1 : batch[i - 1];
    for (int g = bp + 1; g <= b; ++g) gstart[g] = i;
    if (i == N_NODES - 1)
        for (int g = b + 1; g <= N_GRAPHS; ++g) gstart[g] = N_NODES;
}

// ---------------------------------------------------------------------------
// CSR fill — XCD-partitioned (R9, confirmed win)
// ---------------------------------------------------------------------------
__global__ __launch_bounds__(256) void fill_seg_kernel(const int* __restrict__ src,
                                                       const int* __restrict__ dst,
                                                       const int* __restrict__ starts,
                                                       int* __restrict__ cursor,
                                                       u16* __restrict__ csr) {
    const int seg = blockIdx.x & 7;
    const int lo = seg * SEG_SZ, hi = lo + SEG_SZ;
    int e = (blockIdx.x >> 3) * (256 * EPT) + threadIdx.x;
    #pragma unroll
    for (int j = 0; j < EPT; ++j, e += 256) {
        if (e < N_EDGES) {
            int d = dst[e];
            if (d >= lo && d < hi) {
                int p = atomicAdd(&cursor[d], 1);
                csr[starts[d] + p] = (u16)src[e];
            }
        }
    }
}

// ---------------------------------------------------------------------------
// CSR gather mean-aggregation, in-place on the fp8 layer buffer
// ---------------------------------------------------------------------------
template<int DINP>
__global__ __launch_bounds__(256) void csr_agg_kernel(const int* __restrict__ starts,
                                                      const u16* __restrict__ csr,
                                                      u8* __restrict__ abuf) {
    constexpr int STRIDE = 2 * DINP;
    constexpr int LPR = DINP / 16;   // 4 / 8 / 16
    constexpr int EPW = 64 / LPR;    // 16 / 8 / 4
    const int wave = threadIdx.x >> 6, lane = threadIdx.x & 63;
    const int n = blockIdx.x * 4 + wave;
    if (n >= N_NODES) return;
    const int sub = lane / LPR;
    const int li = lane % LPR;
    const int s0 = starts[n], s1 = starts[n + 1];

    float acc[16] = {};
    const u8* xin = abuf + DINP;     // self half

    int e = s0 + sub;
    for (; e + EPW < s1; e += 2 * EPW) {
        int i0 = csr[e], i1 = csr[e + EPW];
        uint4 u0 = *(const uint4*)(xin + (size_t)i0 * STRIDE + li * 16);
        uint4 u1 = *(const uint4*)(xin + (size_t)i1 * STRIDE + li * 16);
        acc16fp8(acc, u0);
        acc16fp8(acc, u1);
    }
    for (; e < s1; e += EPW) {
        int i0 = csr[e];
        uint4 u0 = *(const uint4*)(xin + (size_t)i0 * STRIDE + li * 16);
        acc16fp8(acc, u0);
    }

    #pragma unroll
    for (int off = 32; off >= LPR; off >>= 1) {
        #pragma unroll
        for (int c = 0; c < 16; ++c) acc[c] += __shfl_down(acc[c], off);
    }

    if (lane < LPR) {
        float sc = 1.0f / fmaxf((float)(s1 - s0), 1.0f);
        uint4 o;
        o.x = pack4fp8(acc[0] * sc, acc[1] * sc, acc[2] * sc, acc[3] * sc);
        o.y = pack4fp8(acc[4] * sc, acc[5] * sc, acc[6] * sc, acc[7] * sc);
        o.z = pack4fp8(acc[8] * sc, acc[9] * sc, acc[10] * sc, acc[11] * sc);
        o.w = pack4fp8(acc[12] * sc, acc[13] * sc, acc[14] * sc, acc[15] * sc);
        *(uint4*)(abuf + (size_t)n * STRIDE + li * 16) = o;
    }
}

// ---------------------------------------------------------------------------
// fp8 MFMA GEMM, BK=32 + XOR-swizzled LDS (R13 verbatim — verified 42.5 µs,
// 3.2M conflicts = wave64 floor, 29% occupancy). Do not re-derive bank maps
// without measuring (R17 lesson).
// ---------------------------------------------------------------------------
template<int K, int NB, int ACT>
__global__ __launch_bounds__(256) void gemm_fp8_kernel(
    const u8* __restrict__ A, const u8* __restrict__ W,
    const float* __restrict__ bias,
    u8* __restrict__ out8, int gstride, int goff, int N)
{
    constexpr int NKB = K / 32;
    constexpr int MT = M_PAD / 128;          // 391 m-tiles
    constexpr int MCHUNK = (MT + 7) / 8;     // 49 per XCD
    __shared__ __align__(16) u8 As[3][128 * 32];
    __shared__ __align__(16) u8 Bs[3][128 * 32];

    const int bx = blockIdx.x;
    const int xcd = bx & 7;
    const int seq = bx >> 3;
    const int n = seq % NB;
    const int m = xcd * MCHUNK + seq / NB;
    if (m >= MT) return;
    const int bm = m * 128;
    const int bn = n * 128;

    const int tid = threadIdx.x;
    const int wave = tid >> 6, lane = tid & 63;
    const int wm = (wave & 1) * 64, wn = (wave >> 1) * 64;
    const int lm = lane & 15, lq = lane >> 4;

    const int srow = wave * 32 + (lane >> 1);
    const int scol = ((lane & 1) ^ ((lane >> 3) & 1)) * 16;   // XOR swizzle
    const u8* gA = A + (size_t)(bm + srow) * K + scol;
    const u8* gB = W + (size_t)(bn + srow) * K + scol;
    const int lbase = wave * 32 * 32;

    auto stage = [&](int s, int r) {
        const int ko = s * 32;
        load_lds16(gA + ko, &As[r][lbase]);
        load_lds16(gB + ko, &Bs[r][lbase]);
    };

    floatx4 acc[4][4] = {};

    stage(0, 0);
    stage(1, 1);

    const int csw = (((lq >> 1) ^ ((lm >> 2) & 1)) << 4) + (lq & 1) * 8;

    #pragma unroll
    for (int kb = 0; kb < NKB; ++kb) {
        if (kb + 2 < NKB) stage(kb + 2, (kb + 2) % 3);
        const int rem = NKB - 1 - kb;
        if (rem >= 2)      waitcnt_vm<4>();
        else if (rem == 1) waitcnt_vm<2>();
        else               waitcnt_vm<0>();
        raw_barrier();

        const int r = kb % 3;
        i64 af[4], bfr[4];
        #pragma unroll
        for (int mi = 0; mi < 4; ++mi)
            af[mi] = *(const i64*)&As[r][(wm + mi * 16 + lm) * 32 + csw];
        #pragma unroll
        for (int ni = 0; ni < 4; ++ni)
            bfr[ni] = *(const i64*)&Bs[r][(wn + ni * 16 + lm) * 32 + csw];
        #pragma unroll
        for (int mi = 0; mi < 4; ++mi)
            #pragma unroll
            for (int ni = 0; ni < 4; ++ni)
                acc[mi][ni] = __builtin_amdgcn_mfma_f32_16x16x32_fp8_fp8(
                    af[mi], bfr[ni], acc[mi][ni], 0, 0, 0);
        raw_barrier();
    }

    #pragma unroll
    for (int mi = 0; mi < 4; ++mi) {
        int node0 = bm + wm + mi * 16 + lq * 4;
        #pragma unroll
        for (int ni = 0; ni < 4; ++ni) {
            int o = bn + wn + ni * 16 + lm;
            float bi = bias[o];
            #pragma unroll
            for (int r = 0; r < 4; ++r) {
                int node = node0 + r;
                if (node >= N) continue;
                float v = acc[mi][ni][r] + bi;
                if (ACT == 0) v = (v > 0.0f) ? v : 0.01f * v;
                else          v = fmaxf(v, 0.0f);
                out8[(size_t)node * gstride + goff + o] = f2fp8(v);
            }
        }
    }
}

// ---------------------------------------------------------------------------
// mean pool: 2048 blocks = 512 graphs x 4 column slabs (R12). Raw sums,
// direct disjoint stores.
// ---------------------------------------------------------------------------
__global__ __launch_bounds__(256) void pool_kernel(
    const u8* __restrict__ x3, const int* __restrict__ gstart,
    float* __restrict__ pool)
{
    __shared__ float sacc[32][128];
    const int g = blockIdx.x >> 2;
    const int slab = blockIdx.x & 3;
    const int t = threadIdx.x;
    const int chain = t >> 3;
    const int li = t & 7;
    const int c0 = slab * 128 + li * 16;
    const int n0 = gstart[g], n1 = gstart[g + 1];

    float acc[16] = {};
    for (int n = n0 + chain; n < n1; n += 32) {
        uint4 u = *(const uint4*)(x3 + (size_t)n * 512 + c0);
        acc16fp8(acc, u);
    }
    #pragma unroll
    for (int j = 0; j < 16; ++j) sacc[chain][li * 16 + j] = acc[j];
    __syncthreads();
    if (t < 128) {
        float s = 0.0f;
        #pragma unroll
        for (int r = 0; r < 32; ++r) s += sacc[r][t];
        pool[(size_t)g * 512 + slab * 128 + t] = s;
    }
}

// ---------------------------------------------------------------------------
// dense head with transposed weights (R12); derives 1/cnt from gstart
// ---------------------------------------------------------------------------
__global__ __launch_bounds__(256) void dense_head_kernel(
    const float* __restrict__ pool, const int* __restrict__ gstart,
    const float* __restrict__ Wf1T, const float* __restrict__ bf1,
    const float* __restrict__ Wf2T, const float* __restrict__ bf2,
    const float* __restrict__ Wo,  const float* __restrict__ bo,
    float* __restrict__ out)
{
    __shared__ float sp[512];
    __shared__ float s4[256];
    __shared__ float red[128];
    const int g = blockIdx.x;
    const int t = threadIdx.x;
    const float sc = 1.0f / fmaxf((float)(gstart[g + 1] - gstart[g]), 1.0f);

    sp[t]       = pool[(size_t)g * 512 + t] * sc;
    sp[t + 256] = pool[(size_t)g * 512 + 256 + t] * sc;
    __syncthreads();

    {
        float s = bf1[t];
        #pragma unroll 8
        for (int k = 0; k < 512; ++k) s += sp[k] * Wf1T[(size_t)k * 256 + t];
        s4[t] = fmaxf(s, 0.0f);
    }
    __syncthreads();
    if (t < 128) {
        float s = bf2[t];
        #pragma unroll 8
        for (int k = 0; k < 256; ++k) s += s4[k] * Wf2T[(size_t)k * 128 + t];
        red[t] = fmaxf(s, 0.0f) * Wo[t];
    }
    __syncthreads();
    for (int off = 64; off >= 1; off >>= 1) {
        if (t < off) red[t] += red[t + off];
        __syncthreads();
    }
    if (t == 0) out[g] = 1.0f / (1.0f + expf(-(red[0] + bo[0])));
}

// ---------------------------------------------------------------------------
extern "C" void kernel_launch(void* const* d_in, const int* in_sizes, int n_in,
                              void* d_out, int out_size, void* d_ws, size_t ws_size,
                              hipStream_t stream)
{
    const float* x     = (const float*)d_in[0];
    const int*   ei    = (const int*)  d_in[1];
    const int*   batch = (const int*)  d_in[2];
    const float* Wl1   = (const float*)d_in[3];
    const float* bl1   = (const float*)d_in[4];
    const float* Wr1   = (const float*)d_in[5];
    const float* Wl2   = (const float*)d_in[6];
    const float* bl2   = (const float*)d_in[7];
    const float* Wr2   = (const float*)d_in[8];
    const float* Wl3   = (const float*)d_in[9];
    const float* bl3   = (const float*)d_in[10];
    const float* Wr3   = (const float*)d_in[11];
    const float* Wf1   = (const float*)d_in[12];
    const float* bf1   = (const float*)d_in[13];
    const float* Wf2   = (const float*)d_in[14];
    const float* bf2   = (const float*)d_in[15];
    const float* Wo    = (const float*)d_in[16];
    const float* bo    = (const float*)d_in[17];

    const int* src = ei;
    const int* dst = ei + N_EDGES;

    // ---- workspace layout ----
    char* p = (char*)d_ws;
    auto alloc = [&](size_t bytes) { char* r = p; p += (bytes + 255) & ~(size_t)255; return r; };
    int*   gstart = (int*)  alloc(513 * 4);
    float* pool   = (float*)alloc((size_t)512 * 512 * 4);
    float* Wf1T   = (float*)alloc((size_t)512 * 256 * 4);
    float* Wf2T   = (float*)alloc((size_t)256 * 128 * 4);
    u8*    abuf1  = (u8*)   alloc((size_t)M_PAD * 128);
    u8*    abuf2  = (u8*)   alloc((size_t)M_PAD * 256);
    u8*    abuf3  = (u8*)   alloc((size_t)M_PAD * 512);
    u8*    x3buf8 = (u8*)   alloc((size_t)M_PAD * 512);
    u8*    wb1    = (u8*)   alloc((size_t)128 * 128);
    u8*    wb2    = (u8*)   alloc((size_t)256 * 256);
    u8*    wb3    = (u8*)   alloc((size_t)512 * 512);
    // zero-init block: degi + cursor (one memset)
    char*  zbase  = p;
    int*   degi   = (int*)  alloc(50176 * 4);
    int*   cursor = (int*)  alloc(50176 * 4);
    size_t zbytes = (size_t)(p - zbase);
    int*   starts = (int*)  alloc(50432 * 4);
    int*   bsum   = (int*)  alloc(256 * 4);
    int*   boff   = (int*)  alloc(256 * 4);
    u16*   csr    = (u16*)  alloc((size_t)N_EDGES * 2);

    // ---- CSR build + conversions ----
    hipMemsetAsync(zbase, 0, zbytes, stream);
    const int CONV_N = N_NODES * 16 + 128 * 64 + 256 * 128 + 512 * 256
                     + 256 * 512 + 128 * 256;
    const int CONV_BLOCKS = (CONV_N + 255) / 256;
    prep_kernel<<<COUNT_BLOCKS + CONV_BLOCKS, 256, 0, stream>>>(
        dst, degi, x, Wl1, Wr1, Wl2, Wr2, Wl3, Wr3, Wf1, Wf2,
        abuf1, wb1, wb2, wb3, Wf1T, Wf2T);
    scan1_kernel<<<196, 256, 0, stream>>>(degi, starts, bsum);
    scan2_kernel<<<1, 256, 0, stream>>>(bsum, boff, starts, 196);
    scan3_gstart_kernel<<<196, 256, 0, stream>>>(starts, boff, batch, gstart);
    fill_seg_kernel<<<SEG_BLOCKS * 8, 256, 0, stream>>>(src, dst, starts, cursor, csr);

    const int GB = 12500;
    const int GEMM_GRID = 49 * 8;

    // ---- layer 1: 50 -> 128, leaky_relu ----
    csr_agg_kernel<64><<<GB, 256, 0, stream>>>(starts, csr, abuf1);
    gemm_fp8_kernel<128, 1, 0><<<GEMM_GRID * 1, 256, 0, stream>>>(
        abuf1, wb1, bl1, abuf2, 256, 128, N_NODES);

    // ---- layer 2: 128 -> 256, relu ----
    csr_agg_kernel<128><<<GB, 256, 0, stream>>>(starts, csr, abuf2);
    gemm_fp8_kernel<256, 2, 1><<<GEMM_GRID * 2, 256, 0, stream>>>(
        abuf2, wb2, bl2, abuf3, 512, 256, N_NODES);

    // ---- layer 3: 256 -> 512, relu -> x3 fp8 ----
    csr_agg_kernel<256><<<GB, 256, 0, stream>>>(starts, csr, abuf3);
    gemm_fp8_kernel<512, 4, 1><<<GEMM_GRID * 4, 256, 0, stream>>>(
        abuf3, wb3, bl3, x3buf8, 512, 0, N_NODES);

    // ---- pool + dense head ----
    pool_kernel<<<N_GRAPHS * 4, 256, 0, stream>>>(x3buf8, gstart, pool);
    dense_head_kernel<<<N_GRAPHS, 256, 0, stream>>>(
        pool, gstart, Wf1T, bf1, Wf2T, bf2, Wo, bo, (float*)d_out);
}